// Round 1
// baseline (305.790 us; speedup 1.0000x reference)
//
#include <hip/hip_runtime.h>
#include <cstdint>

typedef unsigned int u32;
typedef unsigned long long u64;

#define B 16
#define A 200000
#define K 300
#define CAP 8192            // per-batch candidate capacity (expected ~4600)

// ---------------------------------------------------------------------------
// Kernel A: scan p_conf, compact candidates (score >= 0.5) into per-batch
// lists of sortable 64-bit keys: (score_bits << 32) | (0xFFFFFFFF - idx).
// Descending key order == lax.top_k order (score desc, index asc on ties).
// Block = 256 threads, each loads one float4; block spans one batch only.
// ---------------------------------------------------------------------------
__global__ __launch_bounds__(256) void scan_kernel(const float* __restrict__ p_conf,
                                                   u64* __restrict__ cand,
                                                   u32* __restrict__ cnt) {
    __shared__ u64 lbuf[1024];
    __shared__ u32 lcnt;
    __shared__ u32 lbase;
    const int b = blockIdx.y;
    const int f4 = blockIdx.x * 256 + threadIdx.x;

    if (threadIdx.x == 0) lcnt = 0;
    __syncthreads();

    if (f4 < A / 4) {
        const float4 c4 = ((const float4*)(p_conf + (size_t)b * A))[f4];
        const float xs[4] = {c4.x, c4.y, c4.z, c4.w};
        #pragma unroll
        for (int e = 0; e < 4; ++e) {
            float s = 1.0f / (1.0f + expf(-xs[e]));
            if (s >= 0.5f) {
                u32 sb  = __float_as_uint(s);
                u32 idx = (u32)(f4 * 4 + e);
                u64 key = ((u64)sb << 32) | (u64)(0xFFFFFFFFu - idx);
                u32 p = atomicAdd(&lcnt, 1u);
                lbuf[p] = key;
            }
        }
    }
    __syncthreads();
    if (threadIdx.x == 0 && lcnt > 0) lbase = atomicAdd(&cnt[b], lcnt);
    __syncthreads();
    const u32 total = lcnt;
    for (u32 t = threadIdx.x; t < total; t += 256) {
        u32 g = lbase + t;
        if (g < CAP) cand[(size_t)b * CAP + g] = lbuf[t];
    }
}

// ---------------------------------------------------------------------------
// Kernel B: one block per batch. Radix-select top-K, bitonic sort boundary,
// decode boxes, IoU bitmask, serial greedy NMS, write outputs.
// ---------------------------------------------------------------------------
__global__ __launch_bounds__(512) void select_nms_kernel(
    const float* __restrict__ p_loc,
    const float* __restrict__ anchors,
    const u64* __restrict__ cand,
    const u32* __restrict__ cnt,
    float* __restrict__ out) {

    __shared__ u32 hist[1024];
    __shared__ u32 sfx[1024];
    __shared__ u64 buf[1024];
    __shared__ float bl[K], bt[K], br[K], bb[K], barea[K], bscore[K];
    __shared__ u64 mask[K][5];
    __shared__ u64 keepw[5];
    __shared__ u32 sh_cut, sh_m;

    const int b   = blockIdx.x;
    const int tid = threadIdx.x;
    const u32 c    = min(cnt[b], (u32)CAP);
    const u32 need = min((u32)K, c);
    const u64* mycand = cand + (size_t)b * CAP;

    for (int i = tid; i < 1024; i += 512) hist[i] = 0;
    if (tid == 0) { sh_m = 0; sh_cut = 1024; }
    __syncthreads();

    // 1024-bin histogram over score bits (scores in [0.5, 1.0) => bits
    // 0x3F000000..0x3F7FFFFF; bin = top 10 mantissa bits, monotone in score).
    for (u32 i = tid; i < c; i += 512) {
        u32 sb  = (u32)(mycand[i] >> 32);
        u32 bin = min((sb - 0x3F000000u) >> 13, 1023u);
        atomicAdd(&hist[bin], 1u);
    }
    __syncthreads();

    // Suffix sums (Hillis-Steele, 2 elems/thread): sfx[t] = #cands with bin >= t
    for (int i = tid; i < 1024; i += 512) sfx[i] = hist[i];
    __syncthreads();
    for (int off = 1; off < 1024; off <<= 1) {
        const int i0 = tid, i1 = tid + 512;
        u32 v0 = sfx[i0] + ((i0 + off < 1024) ? sfx[i0 + off] : 0u);
        u32 v1 = sfx[i1] + ((i1 + off < 1024) ? sfx[i1 + off] : 0u);
        __syncthreads();
        sfx[i0] = v0; sfx[i1] = v1;
        __syncthreads();
    }

    // cutoff = largest bin t with sfx[t] >= need (unique; sfx is decreasing)
    if (need > 0) {
        for (int t = tid; t < 1024; t += 512) {
            if (sfx[t] >= need && (t == 1023 || sfx[t + 1] < need)) sh_cut = (u32)t;
        }
    }
    __syncthreads();

    // Collect candidates with bin >= cutoff (>= need of them, ~need + few)
    const u32 cut = sh_cut;
    for (u32 i = tid; i < c; i += 512) {
        u64 kk  = mycand[i];
        u32 sb  = (u32)(kk >> 32);
        u32 bin = min((sb - 0x3F000000u) >> 13, 1023u);
        if (bin >= cut) {
            u32 p = atomicAdd(&sh_m, 1u);
            if (p < 1024) buf[p] = kk;
        }
    }
    __syncthreads();
    const u32 M = min(sh_m, 1024u);
    u32 P = 2; while (P < M) P <<= 1;
    for (u32 i = M + tid; i < P; i += 512) buf[i] = 0ull;  // pad sinks to tail
    __syncthreads();

    // Bitonic sort descending over P <= 1024 keys
    for (u32 k = 2; k <= P; k <<= 1) {
        for (u32 j = k >> 1; j >= 1; j >>= 1) {
            for (u32 i = tid; i < P; i += 512) {
                u32 l = i ^ j;
                if (l > i) {
                    u64 a = buf[i], d = buf[l];
                    bool asc = ((i & k) != 0);             // segment direction
                    bool sw  = asc ? (a > d) : (a < d);
                    if (sw) { buf[i] = d; buf[l] = a; }
                }
            }
            __syncthreads();
        }
    }

    // Decode boxes for the top-S slots (S = min(K, c)); slots >= S invalid
    const u32 S = need;
    if (tid < K) {
        float l = 0.f, t = 0.f, r = 0.f, btm = 0.f, ar = 0.f, sc = 0.f;
        if ((u32)tid < S) {
            u64 kk = buf[tid];
            sc = __uint_as_float((u32)(kk >> 32));
            u32 aidx = 0xFFFFFFFFu - (u32)(kk & 0xFFFFFFFFull);
            const float4 loc = ((const float4*)p_loc)[(size_t)b * A + aidx];
            const float4 an  = ((const float4*)anchors)[aidx];
            // cxy = a_cxy + loc*0.1*a_wh ; wh = a_wh * exp(loc*0.2) ; ltrb
            float cx = an.x + loc.x * 0.1f * an.z;
            float cy = an.y + loc.y * 0.1f * an.w;
            float w  = an.z * expf(loc.z * 0.2f);
            float h  = an.w * expf(loc.w * 0.2f);
            l = cx - 0.5f * w; t = cy - 0.5f * h;
            r = cx + 0.5f * w; btm = cy + 0.5f * h;
            ar = fmaxf(r - l, 0.0f) * fmaxf(btm - t, 0.0f);
        }
        bl[tid] = l; bt[tid] = t; br[tid] = r; bb[tid] = btm;
        barea[tid] = ar; bscore[tid] = sc;
    }
    __syncthreads();

    // Suppression bitmask: mask[i][w] bit j set iff j>i && iou(i,j) > 0.3
    for (int task = tid; task < K * 5; task += 512) {
        const int i = task / 5, w = task % 5;
        const float li = bl[i], ti = bt[i], ri = br[i], bi = bb[i], ai = barea[i];
        u64 m = 0;
        const int j0 = w * 64, j1 = min(j0 + 64, K);
        for (int j = j0; j < j1; ++j) {
            float lt0 = fmaxf(li, bl[j]);
            float lt1 = fmaxf(ti, bt[j]);
            float rb0 = fminf(ri, br[j]);
            float rb1 = fminf(bi, bb[j]);
            float iw = fmaxf(rb0 - lt0, 0.0f);
            float ih = fmaxf(rb1 - lt1, 0.0f);
            float inter = iw * ih;
            float uni = ai + barea[j] - inter;
            float iou = inter / fmaxf(uni, 1e-9f);
            if (iou > 0.3f && j > i) m |= (1ull << (j & 63));
        }
        mask[i][w] = m;
    }
    __syncthreads();

    // Serial greedy NMS (matches the fori_loop exactly): single thread
    if (tid == 0) {
        u64 kws[5];
        #pragma unroll
        for (int w = 0; w < 5; ++w) {
            int rem = (int)S - w * 64;
            kws[w] = rem <= 0 ? 0ull : (rem >= 64 ? ~0ull : ((1ull << rem) - 1ull));
        }
        for (int i = 0; i < K; ++i) {
            if ((kws[i >> 6] >> (i & 63)) & 1ull) {
                #pragma unroll
                for (int w = 0; w < 5; ++w) kws[w] &= ~mask[i][w];
            }
        }
        #pragma unroll
        for (int w = 0; w < 5; ++w) keepw[w] = kws[w];
    }
    __syncthreads();

    // Outputs (flat concat): ids[4800] | boxes[19200] | labels[4800] |
    //                        scores[4800] | keep[4800]
    if (tid < K) {
        const int g = b * K + tid;
        const bool kept = (keepw[tid >> 6] >> (tid & 63)) & 1ull;
        out[g] = kept ? (float)b : -1.0f;
        float* obox = out + B * K + (size_t)g * 4;
        obox[0] = kept ? bl[tid] : 0.0f;
        obox[1] = kept ? bt[tid] : 0.0f;
        obox[2] = kept ? br[tid] : 0.0f;
        obox[3] = kept ? bb[tid] : 0.0f;
        out[B * K * 5 + g] = kept ? 1.0f : 0.0f;
        out[B * K * 6 + g] = kept ? bscore[tid] : 0.0f;
        out[B * K * 7 + g] = kept ? 1.0f : 0.0f;
    }
}

// ---------------------------------------------------------------------------
extern "C" void kernel_launch(void* const* d_in, const int* in_sizes, int n_in,
                              void* d_out, int out_size, void* d_ws, size_t ws_size,
                              hipStream_t stream) {
    const float* p_loc   = (const float*)d_in[0];
    const float* p_conf  = (const float*)d_in[1];
    // d_in[2] = p_landms: dead compute in reference — never read (saves 128 MB)
    const float* anchors = (const float*)d_in[3];
    float* out = (float*)d_out;

    u64* cand = (u64*)d_ws;                                   // B*CAP u64 = 1 MB
    u32* cnt  = (u32*)((char*)d_ws + (size_t)B * CAP * 8);    // B u32

    hipMemsetAsync(cnt, 0, B * sizeof(u32), stream);          // ws is re-poisoned

    dim3 gridA((A / 4 + 255) / 256, B);                       // 196 x 16 blocks
    scan_kernel<<<gridA, 256, 0, stream>>>(p_conf, cand, cnt);
    select_nms_kernel<<<B, 512, 0, stream>>>(p_loc, anchors, cand, cnt, out);
}

// Round 2
// 285.362 us; speedup vs baseline: 1.0716x; 1.0716x over previous
//
#include <hip/hip_runtime.h>
#include <cstdint>

typedef unsigned int u32;
typedef unsigned long long u64;

#define B 16
#define A 200000
#define K 300
#define CAP 8192            // per-batch candidate capacity (expected ~4600)

// ---------------------------------------------------------------------------
// Kernel A: scan p_conf, compact candidates (score >= 0.5) into per-batch
// lists of sortable 64-bit keys: (score_bits << 32) | (0xFFFFFFFF - idx).
// Descending key order == lax.top_k order (score desc, index asc on ties).
// sigmoid(x) >= 0.5 <=> x >= 0, so prefilter on x >= -0.001 and compute the
// exact sigmoid (same expression as the absmax-0.0 R1 kernel) only for the
// ~2.3% survivors. sigmoid(-0.001) ~= 0.49975 < 0.5, so no decision changes.
// ---------------------------------------------------------------------------
__global__ __launch_bounds__(256) void scan_kernel(const float* __restrict__ p_conf,
                                                   u64* __restrict__ cand,
                                                   u32* __restrict__ cnt) {
    __shared__ u64 lbuf[1024];
    __shared__ u32 lcnt;
    __shared__ u32 lbase;
    const int b = blockIdx.y;
    const int f4 = blockIdx.x * 256 + threadIdx.x;

    if (threadIdx.x == 0) lcnt = 0;
    __syncthreads();

    if (f4 < A / 4) {
        const float4 c4 = ((const float4*)(p_conf + (size_t)b * A))[f4];
        const float xs[4] = {c4.x, c4.y, c4.z, c4.w};
        #pragma unroll
        for (int e = 0; e < 4; ++e) {
            const float x = xs[e];
            if (x >= -0.001f) {                       // cheap prefilter
                float s = 1.0f / (1.0f + expf(-x));   // exact, as in R1
                if (s >= 0.5f) {
                    u32 sb  = __float_as_uint(s);
                    u32 idx = (u32)(f4 * 4 + e);
                    u64 key = ((u64)sb << 32) | (u64)(0xFFFFFFFFu - idx);
                    u32 p = atomicAdd(&lcnt, 1u);
                    lbuf[p] = key;
                }
            }
        }
    }
    __syncthreads();
    if (threadIdx.x == 0 && lcnt > 0) lbase = atomicAdd(&cnt[b], lcnt);
    __syncthreads();
    const u32 total = lcnt;
    for (u32 t = threadIdx.x; t < total; t += 256) {
        u32 g = lbase + t;
        if (g < CAP) cand[(size_t)b * CAP + g] = lbuf[t];
    }
}

// ---------------------------------------------------------------------------
// Kernel B: one block per batch. Radix-select to ~boundary bin, rank-based
// top-K ordering (keys unique), decode, conflict-free IoU bitmask, word-chunk
// serial NMS, write outputs.
// ---------------------------------------------------------------------------
__global__ __launch_bounds__(512) void select_nms_kernel(
    const float* __restrict__ p_loc,
    const float* __restrict__ anchors,
    const u64* __restrict__ cand,
    const u32* __restrict__ cnt,
    float* __restrict__ out) {

    __shared__ u32 hist[512];
    __shared__ u32 sfx[512];
    __shared__ u32 wsum[8];
    __shared__ u64 buf[1024];
    __shared__ u64 skey[K];
    __shared__ float4 bx4[K];
    __shared__ float barea[K];
    __shared__ u64 mask[K][5];
    __shared__ u64 keepw[5];
    __shared__ u32 sh_cut, sh_m;

    const int b    = blockIdx.x;
    const int tid  = threadIdx.x;
    const int lane = tid & 63;
    const int wv   = tid >> 6;
    const u32 c    = min(cnt[b], (u32)CAP);
    const u32 need = min((u32)K, c);
    const u64* mycand = cand + (size_t)b * CAP;

    hist[tid] = 0;
    {   u64* mf = &mask[0][0];
        for (int i = tid; i < K * 5; i += 512) mf[i] = 0ull; }
    if (tid == 0) { sh_m = 0; sh_cut = 0; }
    __syncthreads();

    // ---- 512-bin histogram over score bits (scores in [0.5,1.0)) ----------
    for (u32 i = tid; i < c; i += 512) {
        u32 sb  = (u32)(mycand[i] >> 32);
        u32 bin = min((sb - 0x3F000000u) >> 14, 511u);
        atomicAdd(&hist[bin], 1u);
    }
    __syncthreads();

    // ---- suffix sum via wave shuffles (bin t -> #cands with bin >= t) -----
    u32 s = hist[tid];
    #pragma unroll
    for (int off = 1; off < 64; off <<= 1) {
        u32 t = __shfl_down(s, off, 64);
        if (lane + off < 64) s += t;
    }
    if (lane == 0) wsum[wv] = s;            // wave total = suffix at lane 0
    __syncthreads();
    u32 tail = 0;
    #pragma unroll
    for (int w = 0; w < 8; ++w) if (w > wv) tail += wsum[w];
    sfx[tid] = s + tail;
    __syncthreads();

    // cutoff = largest bin t with sfx[t] >= need (unique since sfx non-incr)
    if (need > 0) {
        if (sfx[tid] >= need && (tid == 511 || sfx[tid + 1] < need)) sh_cut = (u32)tid;
    }
    __syncthreads();

    // ---- collect candidates with bin >= cutoff (~need + boundary bin) -----
    const u32 cut = sh_cut;
    for (u32 i = tid; i < c; i += 512) {
        u64 kk  = mycand[i];
        u32 sb  = (u32)(kk >> 32);
        u32 bin = min((sb - 0x3F000000u) >> 14, 511u);
        if (bin >= cut) {
            u32 p = atomicAdd(&sh_m, 1u);
            if (p < 1024) buf[p] = kk;
        }
    }
    __syncthreads();
    const u32 M = min(sh_m, 1024u);

    // ---- rank-select: rank = #keys greater; keys unique -> permutation ----
    for (u32 t = tid; t < M; t += 512) {
        const u64 mykey = buf[t];
        u32 r = 0;
        #pragma unroll 4
        for (u32 j = 0; j < M; ++j) r += (buf[j] > mykey) ? 1u : 0u;   // broadcast reads
        if (r < (u32)K) skey[r] = mykey;
    }
    __syncthreads();

    // ---- decode boxes for top-S slots ------------------------------------
    const u32 S = need;
    float dl = 0.f, dt = 0.f, dr = 0.f, db = 0.f, dsc = 0.f;
    if (tid < K) {
        float ar = 0.f;
        if ((u32)tid < S) {
            u64 kk = skey[tid];
            dsc = __uint_as_float((u32)(kk >> 32));
            u32 aidx = 0xFFFFFFFFu - (u32)(kk & 0xFFFFFFFFull);
            const float4 loc = ((const float4*)p_loc)[(size_t)b * A + aidx];
            const float4 an  = ((const float4*)anchors)[aidx];
            float cx = an.x + loc.x * 0.1f * an.z;
            float cy = an.y + loc.y * 0.1f * an.w;
            float w  = an.z * expf(loc.z * 0.2f);
            float h  = an.w * expf(loc.w * 0.2f);
            dl = cx - 0.5f * w; dt = cy - 0.5f * h;
            dr = cx + 0.5f * w; db = cy + 0.5f * h;
            ar = fmaxf(dr - dl, 0.0f) * fmaxf(db - dt, 0.0f);
        }
        bx4[tid] = make_float4(dl, dt, dr, db);
        barea[tid] = ar;
    }
    __syncthreads();

    // ---- IoU mask: row r, j > r only; two threads split rows < 212 --------
    {
        int r, j0, st; bool active;
        if (tid < K) { r = tid;     j0 = r + 1; st = (r < 212) ? 2 : 1; active = ((u32)r < S); }
        else         { r = tid - K; j0 = r + 2; st = 2;                 active = ((u32)r < S); }
        if (active) {
            const float4 bi = bx4[r];
            const float  ai = barea[r];
            u64 acc = 0; int wcur = j0 >> 6;
            for (int j = j0; j < (int)S; j += st) {
                const int w = j >> 6;
                if (w != wcur) {
                    if (acc) atomicOr(&mask[r][wcur], acc);
                    acc = 0; wcur = w;
                }
                const float4 bj = bx4[j];
                float lt0 = fmaxf(bi.x, bj.x);
                float lt1 = fmaxf(bi.y, bj.y);
                float rb0 = fminf(bi.z, bj.z);
                float rb1 = fminf(bi.w, bj.w);
                float iw = fmaxf(rb0 - lt0, 0.0f);
                float ih = fmaxf(rb1 - lt1, 0.0f);
                float inter = iw * ih;
                float uni = ai + barea[j] - inter;
                float iou = inter / fmaxf(uni, 1e-9f);   // exact div, as reference
                if (iou > 0.3f) acc |= (1ull << (j & 63));
            }
            if (acc) atomicOr(&mask[r][wcur], acc);
        }
    }
    __syncthreads();

    // ---- serial greedy NMS: 5 static word-chunks, keep word in register ---
    if (tid == 0) {
        u64 k0, k1, k2, k3, k4;
        {
            int rem;
            rem = (int)S - 0;   k0 = rem <= 0 ? 0ull : (rem >= 64 ? ~0ull : ((1ull << rem) - 1ull));
            rem = (int)S - 64;  k1 = rem <= 0 ? 0ull : (rem >= 64 ? ~0ull : ((1ull << rem) - 1ull));
            rem = (int)S - 128; k2 = rem <= 0 ? 0ull : (rem >= 64 ? ~0ull : ((1ull << rem) - 1ull));
            rem = (int)S - 192; k3 = rem <= 0 ? 0ull : (rem >= 64 ? ~0ull : ((1ull << rem) - 1ull));
            rem = (int)S - 256; k4 = rem <= 0 ? 0ull : (rem >= 64 ? ~0ull : ((1ull << rem) - 1ull));
        }
        auto nms_chunk = [&](u64& kw, int wi) {
            int lim = (int)S - wi * 64; if (lim > 64) lim = 64;
            #pragma unroll 8
            for (int bq = 0; bq < lim; ++bq) {
                const u64* row = mask[wi * 64 + bq];
                u64 c0 = row[0], c1 = row[1], c2 = row[2], c3 = row[3], c4v = row[4];
                u64 sl = ((kw >> bq) & 1ull) ? ~0ull : 0ull;
                k0 &= ~(c0 & sl); k1 &= ~(c1 & sl); k2 &= ~(c2 & sl);
                k3 &= ~(c3 & sl); k4 &= ~(c4v & sl);
            }
        };
        nms_chunk(k0, 0); nms_chunk(k1, 1); nms_chunk(k2, 2);
        nms_chunk(k3, 3); nms_chunk(k4, 4);
        keepw[0] = k0; keepw[1] = k1; keepw[2] = k2; keepw[3] = k3; keepw[4] = k4;
    }
    __syncthreads();

    // ---- outputs: ids[4800] | boxes[19200] | labels[4800] | scores[4800] |
    //               keep[4800] -------------------------------------------
    if (tid < K) {
        const int g = b * K + tid;
        const bool kept = (keepw[tid >> 6] >> (tid & 63)) & 1ull;
        out[g] = kept ? (float)b : -1.0f;
        float* obox = out + B * K + (size_t)g * 4;
        obox[0] = kept ? dl : 0.0f;
        obox[1] = kept ? dt : 0.0f;
        obox[2] = kept ? dr : 0.0f;
        obox[3] = kept ? db : 0.0f;
        out[B * K * 5 + g] = kept ? 1.0f : 0.0f;
        out[B * K * 6 + g] = kept ? dsc : 0.0f;
        out[B * K * 7 + g] = kept ? 1.0f : 0.0f;
    }
}

// ---------------------------------------------------------------------------
extern "C" void kernel_launch(void* const* d_in, const int* in_sizes, int n_in,
                              void* d_out, int out_size, void* d_ws, size_t ws_size,
                              hipStream_t stream) {
    const float* p_loc   = (const float*)d_in[0];
    const float* p_conf  = (const float*)d_in[1];
    // d_in[2] = p_landms: dead compute in reference — never read (saves 128 MB)
    const float* anchors = (const float*)d_in[3];
    float* out = (float*)d_out;

    u64* cand = (u64*)d_ws;                                   // B*CAP u64 = 1 MB
    u32* cnt  = (u32*)((char*)d_ws + (size_t)B * CAP * 8);    // B u32

    hipMemsetAsync(cnt, 0, B * sizeof(u32), stream);          // ws is re-poisoned

    dim3 gridA((A / 4 + 255) / 256, B);                       // 196 x 16 blocks
    scan_kernel<<<gridA, 256, 0, stream>>>(p_conf, cand, cnt);
    select_nms_kernel<<<B, 512, 0, stream>>>(p_loc, anchors, cand, cnt, out);
}